// Round 13
// baseline (127.543 us; speedup 1.0000x reference)
//
#include <hip/hip_runtime.h>
#include <math.h>

// z (16,64,64,64) f32 (b,c,h,w), codebook (1024,64) f32. Out: z_q + loss.
#define NB 16
#define NC 64
#define NH 64
#define NW 64
#define NE 1024
#define HW (NH * NW)              // 4096 = 1<<12
#define NTOT (NB * NC * NH * NW)  // 4194304
#define NPIX (NB * NH * NW)       // 65536 pixels (rows)

#define ROWS 64                   // pixels per block
#define NBLK (NPIX / ROWS)        // 1024 blocks

typedef short bf16x8 __attribute__((ext_vector_type(8)));
typedef float f32x4  __attribute__((ext_vector_type(4)));

// fp32 -> bf16 bits, round-to-nearest-even.
__device__ __forceinline__ unsigned short bf16bits(float f) {
    union { float f; unsigned u; } cv;
    cv.f = f;
    const unsigned u = cv.u;
    return (unsigned short)((u + 0x7FFFu + ((u >> 16) & 1u)) >> 16);
}

// ---------------- prep: FRAGMENT-ORDER bf16 codebook + (-0.5||e||^2) ----------------
// cbw layout (16-B units): idx = nt*128 + half*64 + kgrp*16 + col
//   entry e = nt*16 + col; k-chunk = half*4 + kgrp (8 bf16 each).
// Main-loop lane l loads b0/b1 at base + l*16: 64 lanes unit-stride 1 KB.
__global__ void vq_prep_kernel(const float* __restrict__ cb,
                               short* __restrict__ cbw,
                               float* __restrict__ ncbn) {
    const int gid = blockIdx.x * blockDim.x + threadIdx.x;  // 0..4095
    const int e   = gid >> 2;
    const int q   = gid & 3;      // 16-channel quarter: k = q*16 .. q*16+15
    const float4* __restrict__ src = (const float4*)(cb + ((size_t)e << 6) + q * 16);
    float ssq = 0.f;
    bf16x8 pk0, pk1;
    {
        const float4 a = src[0], b = src[1];
        ssq += a.x * a.x + a.y * a.y + a.z * a.z + a.w * a.w
             + b.x * b.x + b.y * b.y + b.z * b.z + b.w * b.w;
        pk0[0] = (short)bf16bits(a.x); pk0[1] = (short)bf16bits(a.y);
        pk0[2] = (short)bf16bits(a.z); pk0[3] = (short)bf16bits(a.w);
        pk0[4] = (short)bf16bits(b.x); pk0[5] = (short)bf16bits(b.y);
        pk0[6] = (short)bf16bits(b.z); pk0[7] = (short)bf16bits(b.w);
    }
    {
        const float4 a = src[2], b = src[3];
        ssq += a.x * a.x + a.y * a.y + a.z * a.z + a.w * a.w
             + b.x * b.x + b.y * b.y + b.z * b.z + b.w * b.w;
        pk1[0] = (short)bf16bits(a.x); pk1[1] = (short)bf16bits(a.y);
        pk1[2] = (short)bf16bits(a.z); pk1[3] = (short)bf16bits(a.w);
        pk1[4] = (short)bf16bits(b.x); pk1[5] = (short)bf16bits(b.y);
        pk1[6] = (short)bf16bits(b.z); pk1[7] = (short)bf16bits(b.w);
    }
    const int nt = e >> 4;
    const int c  = e & 15;
    const int kc0 = 2 * q;        // chunks 2q, 2q+1
    const int idx0 = nt * 128 + (kc0 >> 2) * 64 + (kc0 & 3) * 16 + c;
    const int idx1 = nt * 128 + ((kc0 + 1) >> 2) * 64 + ((kc0 + 1) & 3) * 16 + c;
    ((bf16x8*)cbw)[idx0] = pk0;
    ((bf16x8*)cbw)[idx1] = pk1;
    ssq += __shfl_xor(ssq, 1, 64);
    ssq += __shfl_xor(ssq, 2, 64);
    if (q == 0) ncbn[e] = -0.5f * ssq;
}

// ---------------- main: deferred-argmin pipeline ----------------
// 1024 blocks x 256 thr (4 waves). Wave w sweeps entry quarter w (16 n-tiles,
// dense 32 KB); all 64 rows (4 M-tiles). NEW vs R12: the argmin fold for
// n-tile t runs while n-tile t+1's MFMAs are in flight (one-iteration
// deferral), breaking the MFMA-result -> VALU latency chain that every
// prior variant paid 16x per wave. Full unroll lets loads hoist.
__launch_bounds__(256, 2)
__global__ void vq_main_kernel(const float* __restrict__ z,
                               const short* __restrict__ cbw,
                               const float* __restrict__ ncbn,
                               const float* __restrict__ cb,
                               float* __restrict__ out,
                               float* __restrict__ loss) {
    __shared__ float ncbn_s[NE];                   // 4 KB
    __shared__ float smax4[4][ROWS];               // per-quarter row winners
    __shared__ int   sidx4[4][ROWS];
    __shared__ int   rowi[ROWS];
    __shared__ float swsum[4];

    const int tid  = threadIdx.x;
    const int wave = tid >> 6;     // = entry quarter nq
    const int lane = tid & 63;
    const int bid  = blockIdx.x;

    // stage ncbn (1024 floats) via 256 x float4
    ((float4*)ncbn_s)[tid] = ((const float4*)ncbn)[tid];

    // ---- A fragments direct from global ----
    // m-tile m: row = m*16 + (lane&15); k-chunk (lane>>4)*8 within each half.
    const int rbase = lane & 15;
    const int kbase = (lane >> 4) * 8;
    bf16x8 af[4][2];
    #pragma unroll
    for (int m = 0; m < 4; ++m) {
        const int P = bid * ROWS + m * 16 + rbase;
        const size_t zbm = ((size_t)(P >> 12) << 18) + (P & 4095);
        #pragma unroll
        for (int k0 = 0; k0 < 2; ++k0) {
            const int c0 = k0 * 32 + kbase;
            bf16x8 pk;
            #pragma unroll
            for (int j = 0; j < 8; ++j)
                pk[j] = (short)bf16bits(z[zbm + ((size_t)(c0 + j) << 12)]);
            af[m][k0] = pk;
        }
    }
    __syncthreads();  // ncbn_s ready

    float maxv[4][4];
    int   maxi[4][4];
    #pragma unroll
    for (int m = 0; m < 4; ++m)
        #pragma unroll
        for (int j = 0; j < 4; ++j) { maxv[m][j] = -INFINITY; maxi[m][j] = 0; }

    // ---- sweep this wave's 256 entries, deferred argmin ----
    const int nq = wave;
    const char* __restrict__ bptr =
        (const char*)cbw + (size_t)nq * 16 * 2048 + lane * 16;
    const int c15 = lane & 15;

    // previous-iteration state; sentinel always loses (scores ~ +/-0.01)
    f32x4 accP[4];
    #pragma unroll
    for (int m = 0; m < 4; ++m) accP[m] = (f32x4){-1e30f, -1e30f, -1e30f, -1e30f};
    float ncbP = 0.f;
    int   elP  = 0;

    #pragma unroll
    for (int ntl = 0; ntl < 16; ++ntl) {
        const bf16x8 b0 = *(const bf16x8*)(bptr + ntl * 2048);
        const bf16x8 b1 = *(const bf16x8*)(bptr + ntl * 2048 + 1024);
        const int el    = (nq * 16 + ntl) * 16 + c15;   // global entry
        const float ncb = ncbn_s[el];
        // issue this iteration's MFMAs...
        f32x4 accC[4];
        #pragma unroll
        for (int m = 0; m < 4; ++m) {
            f32x4 a0 = {0.f, 0.f, 0.f, 0.f};
            a0 = __builtin_amdgcn_mfma_f32_16x16x32_bf16(af[m][0], b0, a0, 0, 0, 0);
            accC[m] = __builtin_amdgcn_mfma_f32_16x16x32_bf16(af[m][1], b1, a0, 0, 0, 0);
        }
        // ...and fold the PREVIOUS iteration's scores while they retire
        #pragma unroll
        for (int m = 0; m < 4; ++m) {
            #pragma unroll
            for (int j = 0; j < 4; ++j) {
                const float sc = accP[m][j] + ncbP;
                if (sc > maxv[m][j]) { maxv[m][j] = sc; maxi[m][j] = elP; }
            }
        }
        #pragma unroll
        for (int m = 0; m < 4; ++m) accP[m] = accC[m];
        ncbP = ncb;
        elP  = el;
    }
    // tail fold (ntl = 15)
    #pragma unroll
    for (int m = 0; m < 4; ++m) {
        #pragma unroll
        for (int j = 0; j < 4; ++j) {
            const float sc = accP[m][j] + ncbP;
            if (sc > maxv[m][j]) { maxv[m][j] = sc; maxi[m][j] = elP; }
        }
    }

    // ---- intra-wave argmax across the 16 cols; store per-quarter winners ----
    // element (m, j, lane): row = m*16 + (lane>>4)*4 + j.
    #pragma unroll
    for (int m = 0; m < 4; ++m) {
        #pragma unroll
        for (int j = 0; j < 4; ++j) {
            float v = maxv[m][j];
            int   i = maxi[m][j];
            #pragma unroll
            for (int s = 1; s < 16; s <<= 1) {
                const float ov = __shfl_xor(v, s, 64);
                const int   oi = __shfl_xor(i, s, 64);
                if (ov > v || (ov == v && oi < i)) { v = ov; i = oi; }
            }
            if ((lane & 15) == 0) {
                const int rr = m * 16 + (lane >> 4) * 4 + j;
                smax4[nq][rr] = v;
                sidx4[nq][rr] = i;
            }
        }
    }
    __syncthreads();

    // ---- merge quarters (ascending entry ranges; strict > keeps first idx) ----
    if (tid < ROWS) {
        float v = smax4[0][tid];
        int   i = sidx4[0][tid];
        #pragma unroll
        for (int qq = 1; qq < 4; ++qq) {
            const float ov = smax4[qq][tid];
            if (ov > v) { v = ov; i = sidx4[qq][tid]; }
        }
        rowi[tid] = i;
    }
    __syncthreads();

    // ---- epilogue: gather fp32 codebook row, store out, loss ----
    float lsum = 0.f;
    {
        const int r   = tid & 63;
        const int cq  = tid >> 6;                 // 16 channels: cq*16..+15
        const int P   = bid * ROWS + r;
        const size_t zb = ((size_t)(P >> 12) << 18) + (P & 4095);
        const int mi  = rowi[r];
        const float4* __restrict__ qrow = (const float4*)(cb + ((size_t)mi << 6) + cq * 16);
        #pragma unroll
        for (int q = 0; q < 4; ++q) {
            const float4 q4 = qrow[q];
            const int c = cq * 16 + q * 4;
            const float z0 = z[zb + ((size_t)(c + 0) << 12)];
            const float z1 = z[zb + ((size_t)(c + 1) << 12)];
            const float z2 = z[zb + ((size_t)(c + 2) << 12)];
            const float z3 = z[zb + ((size_t)(c + 3) << 12)];
            out[zb + ((size_t)(c + 0) << 12)] = q4.x;
            out[zb + ((size_t)(c + 1) << 12)] = q4.y;
            out[zb + ((size_t)(c + 2) << 12)] = q4.z;
            out[zb + ((size_t)(c + 3) << 12)] = q4.w;
            const float d0 = q4.x - z0, d1 = q4.y - z1;
            const float d2 = q4.z - z2, d3 = q4.w - z3;
            lsum += d0 * d0 + d1 * d1 + d2 * d2 + d3 * d3;
        }
    }

    #pragma unroll
    for (int off = 32; off > 0; off >>= 1)
        lsum += __shfl_xor(lsum, off, 64);
    if (lane == 0) swsum[wave] = lsum;
    __syncthreads();
    if (tid == 0) {
        const float s = (swsum[0] + swsum[1]) + (swsum[2] + swsum[3]);
        atomicAdd(loss, s * (1.25f / (float)NTOT));  // R7: atomic tail is free
    }
}

extern "C" void kernel_launch(void* const* d_in, const int* in_sizes, int n_in,
                              void* d_out, int out_size, void* d_ws, size_t ws_size,
                              hipStream_t stream) {
    const float* z  = (const float*)d_in[0];
    const float* cb = (const float*)d_in[1];
    float* out  = (float*)d_out;
    float* loss = out + (out_size - 1);

    short* cbw  = (short*)d_ws;                        // [1024][64] bf16, fragment order (128 KB)
    float* ncbn = (float*)(cbw + NE * NC);             // [1024] f32 (4 KB)

    (void)hipMemsetAsync(loss, 0, sizeof(float), stream);
    vq_prep_kernel<<<dim3(16), dim3(256), 0, stream>>>(cb, cbw, ncbn);
    vq_main_kernel<<<dim3(NBLK), dim3(256), 0, stream>>>(z, cbw, ncbn, cb, out, loss);
}

// Round 14
// 94.912 us; speedup vs baseline: 1.3438x; 1.3438x over previous
//
#include <hip/hip_runtime.h>
#include <math.h>

// z (16,64,64,64) f32 (b,c,h,w), codebook (1024,64) f32. Out: z_q + loss.
// R14 = exact revert to R10 (best measured: 95.0 us). R13's deferred-argmin
// spilled (VGPR 128, +33 MB scratch writes) and regressed to 127 us.
#define NB 16
#define NC 64
#define NH 64
#define NW 64
#define NE 1024
#define HW (NH * NW)              // 4096 = 1<<12
#define NTOT (NB * NC * NH * NW)  // 4194304
#define NPIX (NB * NH * NW)       // 65536 pixels (rows)

#define ROWS 128                  // pixels per block
#define NBLK (NPIX / ROWS)        // 512 blocks

typedef short bf16x8 __attribute__((ext_vector_type(8)));
typedef float f32x4  __attribute__((ext_vector_type(4)));

// XOR swizzle within a 128-byte row (A-tile LDS only).
__device__ __forceinline__ int swz(int row, int byteoff) {
    return (byteoff ^ ((row & 7) << 4));
}

// fp32 -> bf16 bits, round-to-nearest-even.
__device__ __forceinline__ unsigned short bf16bits(float f) {
    union { float f; unsigned u; } cv;
    cv.f = f;
    const unsigned u = cv.u;
    return (unsigned short)((u + 0x7FFFu + ((u >> 16) & 1u)) >> 16);
}

// ---------------- prep: FRAGMENT-ORDER bf16 codebook + (-0.5||e||^2) ----------------
// cbw layout (16-B units): idx = nt*128 + half*64 + kgrp*16 + col
//   entry e = nt*16 + col; k-chunk = half*4 + kgrp (8 bf16 each).
// Main-loop lane l loads b0/b1 at base + l*16: 64 lanes unit-stride 1 KB.
__global__ void vq_prep_kernel(const float* __restrict__ cb,
                               short* __restrict__ cbw,
                               float* __restrict__ ncbn) {
    const int gid = blockIdx.x * blockDim.x + threadIdx.x;  // 0..4095
    const int e   = gid >> 2;
    const int q   = gid & 3;      // 16-channel quarter: k = q*16 .. q*16+15
    const float4* __restrict__ src = (const float4*)(cb + ((size_t)e << 6) + q * 16);
    float ssq = 0.f;
    bf16x8 pk0, pk1;
    {
        const float4 a = src[0], b = src[1];
        ssq += a.x * a.x + a.y * a.y + a.z * a.z + a.w * a.w
             + b.x * b.x + b.y * b.y + b.z * b.z + b.w * b.w;
        pk0[0] = (short)bf16bits(a.x); pk0[1] = (short)bf16bits(a.y);
        pk0[2] = (short)bf16bits(a.z); pk0[3] = (short)bf16bits(a.w);
        pk0[4] = (short)bf16bits(b.x); pk0[5] = (short)bf16bits(b.y);
        pk0[6] = (short)bf16bits(b.z); pk0[7] = (short)bf16bits(b.w);
    }
    {
        const float4 a = src[2], b = src[3];
        ssq += a.x * a.x + a.y * a.y + a.z * a.z + a.w * a.w
             + b.x * b.x + b.y * b.y + b.z * b.z + b.w * b.w;
        pk1[0] = (short)bf16bits(a.x); pk1[1] = (short)bf16bits(a.y);
        pk1[2] = (short)bf16bits(a.z); pk1[3] = (short)bf16bits(a.w);
        pk1[4] = (short)bf16bits(b.x); pk1[5] = (short)bf16bits(b.y);
        pk1[6] = (short)bf16bits(b.z); pk1[7] = (short)bf16bits(b.w);
    }
    const int nt = e >> 4;
    const int c  = e & 15;
    const int kc0 = 2 * q;        // chunks 2q, 2q+1
    const int idx0 = nt * 128 + (kc0 >> 2) * 64 + (kc0 & 3) * 16 + c;
    const int idx1 = nt * 128 + ((kc0 + 1) >> 2) * 64 + ((kc0 + 1) & 3) * 16 + c;
    ((bf16x8*)cbw)[idx0] = pk0;
    ((bf16x8*)cbw)[idx1] = pk1;
    ssq += __shfl_xor(ssq, 1, 64);
    ssq += __shfl_xor(ssq, 2, 64);
    if (q == 0) ncbn[e] = -0.5f * ssq;
}

// ---------------- main: 8 waves/block (4 waves/SIMD), 4-way split-N ----------------
// 512 blocks x 512 thr. Wave w: rows (w&1)*64..+63 (4 M-tiles),
// entries (w>>1)*256..+255 (16 n-tiles, dense 32 KB/wave, 128 MB total).
__launch_bounds__(512, 4)
__global__ void vq_main_kernel(const float* __restrict__ z,
                               const short* __restrict__ cbw,
                               const float* __restrict__ ncbn,
                               const float* __restrict__ cb,
                               float* __restrict__ out,
                               float* __restrict__ pbuf) {
    __shared__ __align__(16) short zt[ROWS * 64];  // 16 KB, swizzled
    __shared__ float ncbn_s[NE];                   // 4 KB
    __shared__ float smax4[4][ROWS];               // per-quarter row winners
    __shared__ int   sidx4[4][ROWS];
    __shared__ int   rowi[ROWS];
    __shared__ float swsum[8];

    const int tid  = threadIdx.x;
    const int wave = tid >> 6;
    const int lane = tid & 63;
    const int bid  = blockIdx.x;

    // stage ncbn (1024 floats) via 512 x float2
    ((float2*)ncbn_s)[tid] = ((const float2*)ncbn)[tid];

    // ---- stage z tile: thread -> row (tid&127), channel quarter (tid>>7) ----
    const int r   = tid & 127;
    const int cq  = tid >> 7;                 // 16 channels: cq*16 .. cq*16+15
    const int P   = bid * ROWS + r;
    const int b   = P >> 12;
    const int rem = P & 4095;
    const size_t zb = ((size_t)b << 18) + rem;
    #pragma unroll
    for (int q = 0; q < 2; ++q) {
        bf16x8 pk;
        #pragma unroll
        for (int jj = 0; jj < 8; ++jj) {
            const int c = cq * 16 + q * 8 + jj;
            pk[jj] = (short)bf16bits(z[zb + ((size_t)c << 12)]);
        }
        const int boff = (cq * 16 + q * 8) * 2;
        *(bf16x8*)((char*)zt + r * 128 + swz(r, boff)) = pk;
    }
    __syncthreads();

    // ---- A fragments: wave w rows (w&1)*64 + m*16 + (lane&15) ----
    bf16x8 af[4][2];
    #pragma unroll
    for (int m = 0; m < 4; ++m) {
        const int rr = (wave & 1) * 64 + m * 16 + (lane & 15);
        af[m][0] = *(const bf16x8*)((const char*)zt + rr * 128 + swz(rr, 0  + (lane >> 4) * 16));
        af[m][1] = *(const bf16x8*)((const char*)zt + rr * 128 + swz(rr, 64 + (lane >> 4) * 16));
    }

    float maxv[4][4];
    int   maxi[4][4];
    #pragma unroll
    for (int m = 0; m < 4; ++m)
        #pragma unroll
        for (int j = 0; j < 4; ++j) { maxv[m][j] = -INFINITY; maxi[m][j] = 0; }

    // ---- sweep this wave's 256 entries: 16 n-tiles, dense 1 KB loads ----
    const int nq = wave >> 1;                      // entry quarter 0..3
    const char* __restrict__ bptr =
        (const char*)cbw + (size_t)nq * 16 * 2048 + lane * 16;
    const int c15 = lane & 15;
    #pragma unroll 4
    for (int ntl = 0; ntl < 16; ++ntl) {
        const bf16x8 b0 = *(const bf16x8*)(bptr + ntl * 2048);
        const bf16x8 b1 = *(const bf16x8*)(bptr + ntl * 2048 + 1024);
        const int el    = (nq * 16 + ntl) * 16 + c15;   // global entry
        const float ncb = ncbn_s[el];
        #pragma unroll
        for (int m = 0; m < 4; ++m) {
            f32x4 acc = {0.f, 0.f, 0.f, 0.f};
            acc = __builtin_amdgcn_mfma_f32_16x16x32_bf16(af[m][0], b0, acc, 0, 0, 0);
            acc = __builtin_amdgcn_mfma_f32_16x16x32_bf16(af[m][1], b1, acc, 0, 0, 0);
            #pragma unroll
            for (int j = 0; j < 4; ++j) {
                const float sc = acc[j] + ncb;
                if (sc > maxv[m][j]) { maxv[m][j] = sc; maxi[m][j] = el; }
            }
        }
    }

    // ---- intra-wave argmax across the 16 cols; store per-quarter winners ----
    // element (m, j, lane): row = (wave&1)*64 + m*16 + (lane>>4)*4 + j.
    #pragma unroll
    for (int m = 0; m < 4; ++m) {
        #pragma unroll
        for (int j = 0; j < 4; ++j) {
            float v = maxv[m][j];
            int   i = maxi[m][j];
            #pragma unroll
            for (int s = 1; s < 16; s <<= 1) {
                const float ov = __shfl_xor(v, s, 64);
                const int   oi = __shfl_xor(i, s, 64);
                if (ov > v || (ov == v && oi < i)) { v = ov; i = oi; }
            }
            if ((lane & 15) == 0) {
                const int rr = (wave & 1) * 64 + m * 16 + (lane >> 4) * 4 + j;
                smax4[nq][rr] = v;
                sidx4[nq][rr] = i;
            }
        }
    }
    __syncthreads();

    // ---- merge quarters (ascending entry ranges; strict > keeps first idx) ----
    if (tid < ROWS) {
        float v = smax4[0][tid];
        int   i = sidx4[0][tid];
        #pragma unroll
        for (int qq = 1; qq < 4; ++qq) {
            const float ov = smax4[qq][tid];
            if (ov > v) { v = ov; i = sidx4[qq][tid]; }
        }
        rowi[tid] = i;
    }
    __syncthreads();

    // ---- epilogue: gather fp32 codebook row, store out, loss ----
    float lsum = 0.f;
    {
        const int mi = rowi[r];
        const float4* __restrict__ qrow = (const float4*)(cb + ((size_t)mi << 6) + cq * 16);
        #pragma unroll
        for (int q = 0; q < 4; ++q) {
            const float4 q4 = qrow[q];
            const int c = cq * 16 + q * 4;
            const float z0 = z[zb + ((size_t)(c + 0) << 12)];
            const float z1 = z[zb + ((size_t)(c + 1) << 12)];
            const float z2 = z[zb + ((size_t)(c + 2) << 12)];
            const float z3 = z[zb + ((size_t)(c + 3) << 12)];
            out[zb + ((size_t)(c + 0) << 12)] = q4.x;
            out[zb + ((size_t)(c + 1) << 12)] = q4.y;
            out[zb + ((size_t)(c + 2) << 12)] = q4.z;
            out[zb + ((size_t)(c + 3) << 12)] = q4.w;
            const float d0 = q4.x - z0, d1 = q4.y - z1;
            const float d2 = q4.z - z2, d3 = q4.w - z3;
            lsum += d0 * d0 + d1 * d1 + d2 * d2 + d3 * d3;
        }
    }

    #pragma unroll
    for (int off = 32; off > 0; off >>= 1)
        lsum += __shfl_xor(lsum, off, 64);
    if (lane == 0) swsum[wave] = lsum;
    __syncthreads();
    if (tid == 0) {
        float s = 0.f;
        #pragma unroll
        for (int i = 0; i < 8; ++i) s += swsum[i];
        pbuf[bid] = s;
    }
}

// ---------------- final: reduce 512 partials -> loss ----------------
__global__ void vq_reduce_kernel(const float* __restrict__ pbuf,
                                 float* __restrict__ loss) {
    __shared__ float sw[8];
    const int tid = threadIdx.x;  // 512
    float v = pbuf[tid];
    #pragma unroll
    for (int off = 32; off > 0; off >>= 1)
        v += __shfl_xor(v, off, 64);
    if ((tid & 63) == 0) sw[tid >> 6] = v;
    __syncthreads();
    if (tid == 0) {
        float s = 0.f;
        #pragma unroll
        for (int i = 0; i < 8; ++i) s += sw[i];
        loss[0] = s * (1.25f / (float)NTOT);
    }
}

extern "C" void kernel_launch(void* const* d_in, const int* in_sizes, int n_in,
                              void* d_out, int out_size, void* d_ws, size_t ws_size,
                              hipStream_t stream) {
    const float* z  = (const float*)d_in[0];
    const float* cb = (const float*)d_in[1];
    float* out  = (float*)d_out;
    float* loss = out + (out_size - 1);

    short* cbw  = (short*)d_ws;                        // [1024][64] bf16, fragment order (128 KB)
    float* ncbn = (float*)(cbw + NE * NC);             // [1024] f32 (4 KB)
    float* pbuf = ncbn + NE;                           // [512] f32 partials (2 KB)

    vq_prep_kernel<<<dim3(16), dim3(256), 0, stream>>>(cb, cbw, ncbn);
    vq_main_kernel<<<dim3(NBLK), dim3(512), 0, stream>>>(z, cbw, ncbn, cb, out, pbuf);
    vq_reduce_kernel<<<dim3(1), dim3(512), 0, stream>>>(pbuf, loss);
}